// Round 10
// baseline (1220.579 us; speedup 1.0000x reference)
//
#include <hip/hip_runtime.h>

#define NPG 57       // nodes per graph
#define NEPG 160     // edges per graph
#define NB 80        // branches per graph
#define HID 128
#define NG 4096      // graphs
#define NL 5

typedef __attribute__((ext_vector_type(8))) short bf16x8;
typedef __attribute__((ext_vector_type(4))) float f32x4;
typedef unsigned int u32;

__device__ __forceinline__ short f2bf(float f) {
    u32 u = __builtin_bit_cast(u32, f);
    u += 0x7fff + ((u >> 16) & 1);
    return (short)(u >> 16);
}
__device__ __forceinline__ float bf2f(short s) {
    u32 u = ((u32)(unsigned short)s) << 16;
    return __builtin_bit_cast(float, u);
}
__device__ __forceinline__ u32 packhl(float v) {
    short hi = f2bf(v);
    short lo = f2bf(v - bf2f(hi));
    return (((u32)(unsigned short)hi) << 16) | (u32)(unsigned short)lo;
}
__device__ __forceinline__ float unpackf(u32 u) {
    return bf2f((short)(u >> 16)) + bf2f((short)(u & 0xFFFFu));
}

// unpack 8 packed u32 (two uint4) -> hi/lo bf16x8 fragments
__device__ __forceinline__ void unpack_frag(uint4 a, uint4 b, bf16x8& fh, bf16x8& fl) {
    uint4 h, l;
    h.x = (a.y & 0xFFFF0000u) | (a.x >> 16);
    h.y = (a.w & 0xFFFF0000u) | (a.z >> 16);
    h.z = (b.y & 0xFFFF0000u) | (b.x >> 16);
    h.w = (b.w & 0xFFFF0000u) | (b.z >> 16);
    l.x = (a.y << 16) | (a.x & 0xFFFFu);
    l.y = (a.w << 16) | (a.z & 0xFFFFu);
    l.z = (b.y << 16) | (b.x & 0xFFFFu);
    l.w = (b.w << 16) | (b.z & 0xFFFFu);
    fh = __builtin_bit_cast(bf16x8, h);
    fl = __builtin_bit_cast(bf16x8, l);
}

// read 8 consecutive packed u32 from an LDS row (base rowp), element offset k0,
// byte-XOR swizzle sw (16B granules) -> hi/lo fragments
__device__ __forceinline__ void frag_pk(const u32* rowp, int k0, int sw,
                                        bf16x8& fh, bf16x8& fl) {
    uint4 a = *(const uint4*)((const char*)rowp + ((k0 * 4) ^ sw));
    uint4 b = *(const uint4*)((const char*)rowp + (((k0 + 4) * 4) ^ sw));
    unpack_frag(a, b, fh, fl);
}

// one ks-slice of bf16x3 MFMA over NCT ct-tiles starting at ctbase (B = global wb)
template<int NCT>
__device__ __forceinline__ void mm_ks(f32x4* acc, const bf16x8& fh, const bf16x8& fl,
                                      const short* __restrict__ whi,
                                      const short* __restrict__ wlo,
                                      int ln15, int kb, int ks, int ctbase) {
#pragma unroll
    for (int j = 0; j < NCT; ++j) {
        int ct = ctbase + j;
        bf16x8 bhi = *(const bf16x8*)(whi + (16 * ct + ln15) * HID + kb + 32 * ks);
        bf16x8 blo = *(const bf16x8*)(wlo + (16 * ct + ln15) * HID + kb + 32 * ks);
        f32x4 a = acc[j];
        a = __builtin_amdgcn_mfma_f32_16x16x32_bf16(fh, bhi, a, 0, 0, 0);
        a = __builtin_amdgcn_mfma_f32_16x16x32_bf16(fh, blo, a, 0, 0, 0);
        a = __builtin_amdgcn_mfma_f32_16x16x32_bf16(fl, bhi, a, 0, 0, 0);
        acc[j] = a;
    }
}

// ---- weight prep (unchanged layouts) ----
// wb shorts: [0..229375] conv(5)+P+Q hi/lo pairs (mat*32768 + {0|16384} + n*128+k)
//            [229376..231423] phys hi [16][128]; [231424..233471] phys lo
// fsc/fsh: folded BN scale/shift [5][128] floats
__global__ void prep(const float* __restrict__ convW, const float* __restrict__ mlpW1,
                     const float* __restrict__ physW1, const float* __restrict__ convb,
                     const float* __restrict__ bn_gamma, const float* __restrict__ bn_beta,
                     const float* __restrict__ bn_mean, const float* __restrict__ bn_var,
                     short* __restrict__ wb, float* __restrict__ fsc, float* __restrict__ fsh) {
    int id = blockIdx.x * 256 + threadIdx.x;
    if (id < 114688) {
        int mat = id >> 14, rem = id & 16383, n = rem >> 7, k = rem & 127;
        float w;
        if (mat < 5)       w = convW[mat * 16384 + k * 128 + n];
        else if (mat == 5) w = mlpW1[k * 128 + n];
        else               w = mlpW1[(128 + k) * 128 + n];
        short hi = f2bf(w);
        short lo = f2bf(w - bf2f(hi));
        wb[mat * 32768 + n * 128 + k] = hi;
        wb[mat * 32768 + 16384 + n * 128 + k] = lo;
    } else if (id < 116736) {
        int p = id - 114688, n = p >> 7, k = p & 127;
        float w = physW1[k * 16 + n];
        short hi = f2bf(w);
        short lo = f2bf(w - bf2f(hi));
        wb[229376 + p] = hi;
        wb[231424 + p] = lo;
    } else if (id < 117376) {
        int p = id - 116736;
        float sc = bn_gamma[p] * rsqrtf(bn_var[p] + 1e-5f);
        float sh = fmaf(convb[p] - bn_mean[p], sc, bn_beta[p]);
        fsc[p] = sc;
        fsh[p] = sh;
    }
}

// Dense-A design: aggregation as MFMA (A-frags register-resident across layers),
// h kept channel-major packed bf16 hi|lo (hTu). 1024 threads = 16 waves:
// wave = (r-tile = wv&3) x (c-quarter = wv>>2). 84KB LDS -> 1 block/CU, 16 waves.
__global__ __launch_bounds__(1024, 4) void pinn_fused(
    const float* __restrict__ x, const int* __restrict__ edge_index,
    const int* __restrict__ branch_u, const int* __restrict__ branch_v,
    const float* __restrict__ Wp, const float* __restrict__ bp,
    const float* __restrict__ physb1, const float* __restrict__ physW2,
    const float* __restrict__ physb2,
    const float* __restrict__ mlpW1, const float* __restrict__ mlpb1,
    const float* __restrict__ mlpW2, const float* __restrict__ mlpb2,
    const short* __restrict__ wb, const float* __restrict__ fsc,
    const float* __restrict__ fsh, float* __restrict__ out) {
    __shared__ u32  hTu[128][64];     // 32 KB: h^T packed (hi<<16|lo), swizzled by (c&7)<<4
    __shared__ u32  pool[64 * 128];   // 32 KB: Af32 -> mpk[64][128] -> hrowpk[64][128]
    __shared__ short Ahi[64 * 64];    // 8 KB
    __shared__ short Alo[64 * 64];    // 8 KB
    __shared__ float dinv[64];
    __shared__ int   deg[64];
    __shared__ short esrc[NEPG], edst[NEPG];
    __shared__ float theta[64];
    __shared__ float red[NB];
    __shared__ int   bu[NB], bv[NB];

    const int g = blockIdx.x;
    const int tid = threadIdx.x;
    const int lane = tid & 63;
    const int wv = tid >> 6;            // 0..15
    const int ln15 = lane & 15;
    const int hi4 = lane >> 4;
    const int kb = hi4 << 3;
    const int R0 = 16 * (wv & 3);       // row tile base
    const int ct0 = 2 * (wv >> 2);      // first of this wave's 2 c-tiles

    // ---- projection into hTu (wave wv handles channels 8wv..8wv+7; lane = node) ----
    {
        int r = lane;
        float4 xv = make_float4(0.f, 0.f, 0.f, 0.f);
        if (r < NPG) xv = ((const float4*)x)[g * NPG + r];
        for (int c = 8 * wv; c < 8 * wv + 8; ++c) {
            float h0 = 0.f;
            if (r < NPG)
                h0 = fmaf(xv.x, Wp[c], fmaf(xv.y, Wp[HID + c],
                     fmaf(xv.z, Wp[2 * HID + c], fmaf(xv.w, Wp[3 * HID + c], bp[c]))));
            *(u32*)((char*)&hTu[c][0] + ((r * 4) ^ ((c & 7) << 4))) = packhl(h0);
        }
    }
    if (tid < 64) deg[tid] = (tid < NPG) ? 1 : 0;   // self-loop
    if (tid < NB) { bu[tid] = branch_u[tid]; bv[tid] = branch_v[tid]; red[tid] = 0.f; }
    {   // zero A (f32 view of pool)
        float* Af = (float*)pool;
        for (int i = tid; i < 4096; i += 1024) Af[i] = 0.f;
    }
    __syncthreads();

    if (tid < NEPG) {
        int gs = edge_index[g * NEPG + tid];
        int gd = edge_index[NG * NEPG + g * NEPG + tid];
        esrc[tid] = (short)(gs - g * NPG);
        edst[tid] = (short)(gd - g * NPG);
        atomicAdd(&deg[edst[tid]], 1);
    }
    __syncthreads();
    if (tid < 64) dinv[tid] = (tid < NPG) ? rsqrtf((float)deg[tid]) : 0.f;
    __syncthreads();
    {   // build dense normalized A (incl. self-loops) in f32
        float* Af = (float*)pool;
        if (tid < NEPG) {
            int s = esrc[tid], d = edst[tid];
            atomicAdd(&Af[d * 64 + s], dinv[s] * dinv[d]);
        }
        if (tid < NPG) atomicAdd(&Af[tid * 64 + tid], dinv[tid] * dinv[tid]);
    }
    __syncthreads();
    {   // convert A -> bf16 hi/lo (row-major, read-once so no swizzle needed)
        const float* Af = (const float*)pool;
        for (int i = tid; i < 4096; i += 1024) {
            float a = Af[i];
            short hi = f2bf(a);
            Ahi[i] = hi;
            Alo[i] = f2bf(a - bf2f(hi));
        }
    }
    __syncthreads();

    // A-fragments register-resident for all 5 layers (rows R0+ln15, k = s)
    bf16x8 afh[2], afl[2];
#pragma unroll
    for (int ks2 = 0; ks2 < 2; ++ks2) {
        int off = (R0 + ln15) * 64 + 32 * ks2 + kb;
        afh[ks2] = *(const bf16x8*)&Ahi[off];
        afl[ks2] = *(const bf16x8*)&Alo[off];
    }

    // ---- 5 GCN layers: MFMA1 (m = A@h) -> mpk -> MFMA2 (z = m@W) -> BN/ReLU/residual ----
    u32* mpk = pool;
    for (int l = 0; l < NL; ++l) {
        // MFMA1: output rows R0..R0+15, cols tiles ct0, ct0+1; k = s (64, 2 steps)
        f32x4 acc[2];
        acc[0] = (f32x4){0.f, 0.f, 0.f, 0.f};
        acc[1] = (f32x4){0.f, 0.f, 0.f, 0.f};
#pragma unroll
        for (int ks2 = 0; ks2 < 2; ++ks2) {
#pragma unroll
            for (int j = 0; j < 2; ++j) {
                int c = 16 * (ct0 + j) + ln15;
                bf16x8 hh, hl;
                frag_pk(&hTu[c][0], 32 * ks2 + kb, (c & 7) << 4, hh, hl);
                f32x4 a = acc[j];
                a = __builtin_amdgcn_mfma_f32_16x16x32_bf16(afh[ks2], hh, a, 0, 0, 0);
                a = __builtin_amdgcn_mfma_f32_16x16x32_bf16(afh[ks2], hl, a, 0, 0, 0);
                a = __builtin_amdgcn_mfma_f32_16x16x32_bf16(afl[ks2], hh, a, 0, 0, 0);
                acc[j] = a;
            }
        }
        // write m packed (row-major, swizzled)
#pragma unroll
        for (int j = 0; j < 2; ++j) {
#pragma unroll
            for (int q = 0; q < 4; ++q) {
                int rr = R0 + 4 * hi4 + q;
                int cc = 16 * (ct0 + j) + ln15;
                *(u32*)((char*)&mpk[rr * 128] + ((cc * 4) ^ ((rr & 7) << 4))) =
                    packhl(acc[j][q]);
            }
        }
        __syncthreads();

        // MFMA2: z = m @ W (k = 128, 4 steps); A-frags from mpk, B from global wb
        f32x4 z2[2];
        z2[0] = (f32x4){0.f, 0.f, 0.f, 0.f};
        z2[1] = (f32x4){0.f, 0.f, 0.f, 0.f};
        const short* whi = wb + 2 * l * 16384;
        const short* wlo = wb + (2 * l + 1) * 16384;
#pragma unroll
        for (int ks = 0; ks < 4; ++ks) {
            bf16x8 mh, ml;
            int rr = R0 + ln15;
            frag_pk(&mpk[rr * 128], 32 * ks + kb, (rr & 7) << 4, mh, ml);
            mm_ks<2>(z2, mh, ml, whi, wlo, ln15, kb, ks, ct0);
        }
        if (l == NL - 1) __syncthreads();   // hrowpk aliases mpk: drain all reads first

        // epilogue: BN -> ReLU -> + residual (in hTu layout); last layer -> hrowpk
        const float* sc = fsc + l * HID;
        const float* sh = fsh + l * HID;
#pragma unroll
        for (int j = 0; j < 2; ++j) {
            int cc = 16 * (ct0 + j) + ln15;
            float scv = sc[cc], shv = sh[cc];
#pragma unroll
            for (int q = 0; q < 4; ++q) {
                int rr = R0 + 4 * hi4 + q;
                u32* hp = (u32*)((char*)&hTu[cc][0] + ((rr * 4) ^ ((cc & 7) << 4)));
                float hold = unpackf(*hp);
                float hnew = fmaxf(fmaf(z2[j][q], scv, shv), 0.f) + hold;
                if (l == NL - 1)
                    *(u32*)((char*)&pool[rr * 128] + ((cc * 4) ^ ((rr & 7) << 4))) =
                        packhl(hnew);
                else
                    *hp = packhl(hnew);
            }
        }
        __syncthreads();
    }
    // pool now holds final h row-major packed (hrowpk)

    // ---- theta via MFMA (waves 0-3) ----
    if (wv < 4) {
        f32x4 t4 = (f32x4){0.f, 0.f, 0.f, 0.f};
        int r = 16 * wv + ln15;
#pragma unroll
        for (int ks = 0; ks < 4; ++ks) {
            bf16x8 fh, fl;
            frag_pk(&pool[r * 128], 32 * ks + kb, (r & 7) << 4, fh, fl);
            bf16x8 bh = *(const bf16x8*)(wb + 229376 + ln15 * HID + 32 * ks + kb);
            bf16x8 bl = *(const bf16x8*)(wb + 231424 + ln15 * HID + 32 * ks + kb);
            t4 = __builtin_amdgcn_mfma_f32_16x16x32_bf16(fh, bh, t4, 0, 0, 0);
            t4 = __builtin_amdgcn_mfma_f32_16x16x32_bf16(fh, bl, t4, 0, 0, 0);
            t4 = __builtin_amdgcn_mfma_f32_16x16x32_bf16(fl, bh, t4, 0, 0, 0);
        }
        float b1 = physb1[ln15], w2 = physW2[ln15], b2 = physb2[0];
#pragma unroll
        for (int q = 0; q < 4; ++q) {
            float val = fmaxf(t4[q] + b1, 0.f) * w2;
#pragma unroll
            for (int o = 1; o < 16; o <<= 1) val += __shfl_xor(val, o, 16);
            int rq = 16 * wv + 4 * hi4 + q;
            if (ln15 == 0 && rq < NPG) theta[rq] = val + b2;
        }
    }
    __syncthreads();

    // ---- branch-direct edge MLP: 10 (branch-tile x c-half) tasks over 16 waves ----
    for (int task = wv; task < 10; task += 16) {
        int t = task >> 1;
        int cb = (task & 1) * 4;
        int b = 16 * t + ln15;
        int ru = bu[b], rv = bv[b];
        f32x4 acc4[4];
#pragma unroll
        for (int j = 0; j < 4; ++j) acc4[j] = (f32x4){0.f, 0.f, 0.f, 0.f};
#pragma unroll
        for (int ks = 0; ks < 4; ++ks) {
            bf16x8 fh, fl;
            frag_pk(&pool[ru * 128], 32 * ks + kb, (ru & 7) << 4, fh, fl);
            mm_ks<4>(acc4, fh, fl, wb + 10 * 16384, wb + 11 * 16384, ln15, kb, ks, cb);
            frag_pk(&pool[rv * 128], 32 * ks + kb, (rv & 7) << 4, fh, fl);
            mm_ks<4>(acc4, fh, fl, wb + 12 * 16384, wb + 13 * 16384, ln15, kb, ks, cb);
        }
        float dth[4];
#pragma unroll
        for (int q = 0; q < 4; ++q) {
            int bb = 16 * t + 4 * hi4 + q;
            dth[q] = theta[bu[bb]] - theta[bv[bb]];
        }
        float sums[4] = {0.f, 0.f, 0.f, 0.f};
#pragma unroll
        for (int j = 0; j < 4; ++j) {
            int ch = 16 * (cb + j) + ln15;
            float w256 = mlpW1[256 * HID + ch];
            float b1 = mlpb1[ch];
            float w2 = mlpW2[ch];
#pragma unroll
            for (int q = 0; q < 4; ++q)
                sums[q] += fmaxf(fmaf(dth[q], w256, acc4[j][q] + b1), 0.f) * w2;
        }
#pragma unroll
        for (int q = 0; q < 4; ++q) {
#pragma unroll
            for (int o = 1; o < 16; o <<= 1) sums[q] += __shfl_xor(sums[q], o, 16);
            if (ln15 == 0) atomicAdd(&red[16 * t + 4 * hi4 + q], sums[q]);
        }
    }
    __syncthreads();
    if (tid < NB) out[g * NB + tid] = red[tid] + mlpb2[0];
}

extern "C" void kernel_launch(void* const* d_in, const int* in_sizes, int n_in,
                              void* d_out, int out_size, void* d_ws, size_t ws_size,
                              hipStream_t stream) {
    const float* x          = (const float*)d_in[0];
    const int*   edge_index = (const int*)d_in[1];
    const int*   branch_u   = (const int*)d_in[2];
    const int*   branch_v   = (const int*)d_in[3];
    const float* Wp         = (const float*)d_in[4];
    const float* bp         = (const float*)d_in[5];
    const float* convW      = (const float*)d_in[6];
    const float* convb      = (const float*)d_in[7];
    const float* bn_gamma   = (const float*)d_in[8];
    const float* bn_beta    = (const float*)d_in[9];
    const float* bn_mean    = (const float*)d_in[10];
    const float* bn_var     = (const float*)d_in[11];
    const float* physW1     = (const float*)d_in[12];
    const float* physb1     = (const float*)d_in[13];
    const float* physW2     = (const float*)d_in[14];
    const float* physb2     = (const float*)d_in[15];
    const float* mlpW1      = (const float*)d_in[16];
    const float* mlpb1      = (const float*)d_in[17];
    const float* mlpW2      = (const float*)d_in[18];
    const float* mlpb2      = (const float*)d_in[19];
    float* out = (float*)d_out;

    short* wb = (short*)d_ws;                          // 466944 B
    float* fsc = (float*)((char*)d_ws + 466944);       // 5*128 floats
    float* fsh = fsc + 640;

    prep<<<459, 256, 0, stream>>>(convW, mlpW1, physW1, convb,
                                  bn_gamma, bn_beta, bn_mean, bn_var, wb, fsc, fsh);
    pinn_fused<<<NG, 1024, 0, stream>>>(
        x, edge_index, branch_u, branch_v, Wp, bp,
        physb1, physW2, physb2, mlpW1, mlpb1, mlpW2, mlpb2,
        wb, fsc, fsh, out);
}